// Round 1
// baseline (505.007 us; speedup 1.0000x reference)
//
#include <hip/hip_runtime.h>
#include <math.h>

typedef _Float16 f16;
typedef _Float16 f16x4 __attribute__((ext_vector_type(4)));
typedef _Float16 f16x8 __attribute__((ext_vector_type(8)));
typedef float    f32x4 __attribute__((ext_vector_type(4)));

#define NSEQ 1024
#define CD   128
#define LT   136   // pre-kernel LDS f16 row stride (272 B = 17*16 B, keeps b128 alignment)

// khs: [bh][g16 0..63][cs 0..3][lane 0..63][j 0..7]   (131072 f16 per bh)
//   value = Ktr[key = (g16>>1)*32 + 8*(lq>>2) + 4*(g16&1) + (lq&3)][c = cs*32+quad*8+j]
// vhs: [bh][k32 0..31][cb 0..7][lane 0..63][j 0..7]
//   value = Vtr[key = k32*32 + quad*8 + j][c = cb*16 + lq]
// Both are exact MFMA fragment order: a wave's frag load = base + lane*16B (coalesced 1KB).

__global__ __launch_bounds__(256)
void ipa_pre(const float* __restrict__ kg, const float* __restrict__ vg,
             const float* __restrict__ Lm, f16* __restrict__ khs, f16* __restrict__ vhs)
{
    __shared__ float LL[64 * 16];
    __shared__ __align__(16) f16 Kt[64 * LT];
    __shared__ __align__(16) f16 Vt[64 * LT];
    const int bx = blockIdx.x, nt = blockIdx.y, tid = threadIdx.x;
    const int bh = ((bx & 7) << 3) | (bx >> 3);   // XCD x <-> bh 8x..8x+7 (matches attn)
    const int b  = bh >> 3;
    const float* Lb = Lm + ((size_t)b * NSEQ + nt * 64) * 16;
    for (int t = tid; t < 64 * 16; t += 256) LL[t] = Lb[t];
    __syncthreads();

    const size_t base = ((size_t)bh * NSEQ + nt * 64) * CD;
    #pragma unroll
    for (int it = 0; it < 8; ++it) {
        int g = it * 256 + tid;
        int row = g >> 5, cg = g & 31;
        size_t idx = base + row * CD + cg * 4;
        const float* Lr = &LL[row * 16];
        float4 xk = *(const float4*)(kg + idx);
        float4 xv = *(const float4*)(vg + idx);
        float4 yk = xk, yv = xv;
        if (cg >= 2) {
            float t0 = xk.x, t1 = -xk.y, t2 = -xk.z, t3 = -xk.w;   // K: M = L^T eta
            yk.x = Lr[0]*t0 + Lr[4]*t1 + Lr[8] *t2 + Lr[12]*t3;
            yk.y = Lr[1]*t0 + Lr[5]*t1 + Lr[9] *t2 + Lr[13]*t3;
            yk.z = Lr[2]*t0 + Lr[6]*t1 + Lr[10]*t2 + Lr[14]*t3;
            yk.w = Lr[3]*t0 + Lr[7]*t1 + Lr[11]*t2 + Lr[15]*t3;
            t0 = xv.x; t1 = -xv.y; t2 = -xv.z; t3 = -xv.w;         // V: M = eta L^T eta
            yv.x =  (Lr[0]*t0 + Lr[4]*t1 + Lr[8] *t2 + Lr[12]*t3);
            yv.y = -(Lr[1]*t0 + Lr[5]*t1 + Lr[9] *t2 + Lr[13]*t3);
            yv.z = -(Lr[2]*t0 + Lr[6]*t1 + Lr[10]*t2 + Lr[14]*t3);
            yv.w = -(Lr[3]*t0 + Lr[7]*t1 + Lr[11]*t2 + Lr[15]*t3);
        }
        f16x4 hk = {(f16)yk.x, (f16)yk.y, (f16)yk.z, (f16)yk.w};
        f16x4 hv = {(f16)yv.x, (f16)yv.y, (f16)yv.z, (f16)yv.w};
        *(f16x4*)&Kt[row * LT + cg * 4] = hk;
        *(f16x4*)&Vt[row * LT + cg * 4] = hv;
    }
    __syncthreads();

    // staged K out (b128 LDS read -> fully coalesced global store)
    f16* kout = khs + (size_t)bh * 131072 + (size_t)nt * 4 * 4 * 512;
    #pragma unroll
    for (int it = 0; it < 4; ++it) {
        int slot = it * 256 + tid;                 // (g16l, cs, L)
        int g16l = slot >> 8, cs = (slot >> 6) & 3, L = slot & 63;
        int lq = L & 15, quad = L >> 4;
        int keyl = ((g16l >> 1) << 5) + ((lq >> 2) << 3) + ((g16l & 1) << 2) + (lq & 3);
        f16x8 kv = *(const f16x8*)&Kt[keyl * LT + cs * 32 + quad * 8];
        *(f16x8*)(kout + (g16l * 4 + cs) * 512 + L * 8) = kv;
    }
    // staged V^T out (scalar LDS column reads -> coalesced global store)
    f16* vout = vhs + (size_t)bh * 131072 + (size_t)nt * 2 * 8 * 512;
    #pragma unroll
    for (int it = 0; it < 4; ++it) {
        int slot = it * 256 + tid;                 // (k32l, cb, L)
        int k32l = slot >> 9, cb = (slot >> 6) & 7, L = slot & 63;
        int lq = L & 15, quad = L >> 4;
        int c = cb * 16 + lq;
        f16x8 o;
        #pragma unroll
        for (int j = 0; j < 8; ++j)
            o[j] = Vt[(k32l * 32 + quad * 8 + j) * LT + c];
        *(f16x8*)(vout + (k32l * 8 + cb) * 512 + L * 8) = o;
    }
}

// ---------------- attention: key-split flash, 4 waves/block ----------------
// Wave w: q-tile (w>>1), key-half (w&1).  Pairs merge (m,l,oacc) via LDS at the end.
// No barriers in the hot loop.  4096 waves total -> 4 waves/SIMD (VGPR<=128).
__global__ __launch_bounds__(256, 4)
void ipa_attn(const float* __restrict__ qg, const f16* __restrict__ khs,
              const f16* __restrict__ vhs, const float* __restrict__ Lm,
              float* __restrict__ out)
{
    __shared__ __align__(16) float mrg[2][64][68];   // [pair][lane][oacc 0..63, m0,l0,m1,l1]
    const int n = blockIdx.x;
    const int bh = ((n & 7) << 3) | ((n >> 3) & 7);   // XCD x (n%8) handles bh 8x..8x+7
    const int b  = bh >> 3;
    const int tid = threadIdx.x;
    const int w = tid >> 6, lane = tid & 63, lq = lane & 15, quad = lane >> 4;
    const int qw = (n >> 6) * 2 + (w >> 1);           // 0..31
    const int kh = w & 1;                             // key half
    const int q0 = qw * 32;
    const f16* kbh = khs + (size_t)bh * 131072;
    const f16* vbh = vhs + (size_t)bh * 131072;
    const float sc2 = 0.12751744154226873f;           // (1/sqrt(128)) * log2(e)

    // ---- Q: load fp32, transform (M = eta L^T eta) per-lane, scale, make frags ----
    f16x8 qf[2][4];
    #pragma unroll
    for (int u = 0; u < 2; ++u) {
        int qrow = q0 + u * 16 + lq;
        const float* Lr = Lm + ((size_t)b * NSEQ + qrow) * 16;
        const float* qp = qg + ((size_t)bh * NSEQ + qrow) * CD;
        float Lv[16];
        #pragma unroll
        for (int i = 0; i < 4; ++i) *(float4*)&Lv[i*4] = *(const float4*)(Lr + i*4);
        #pragma unroll
        for (int cs = 0; cs < 4; ++cs) {
            int c0 = cs * 32 + quad * 8;
            float4 x0 = *(const float4*)(qp + c0);
            float4 x1 = *(const float4*)(qp + c0 + 4);
            if (c0 >= 8) {
                float t0 = x0.x, t1 = -x0.y, t2 = -x0.z, t3 = -x0.w;
                float4 y;
                y.x =  (Lv[0]*t0 + Lv[4]*t1 + Lv[8] *t2 + Lv[12]*t3);
                y.y = -(Lv[1]*t0 + Lv[5]*t1 + Lv[9] *t2 + Lv[13]*t3);
                y.z = -(Lv[2]*t0 + Lv[6]*t1 + Lv[10]*t2 + Lv[14]*t3);
                y.w = -(Lv[3]*t0 + Lv[7]*t1 + Lv[11]*t2 + Lv[15]*t3);
                x0 = y;
                t0 = x1.x; t1 = -x1.y; t2 = -x1.z; t3 = -x1.w;
                y.x =  (Lv[0]*t0 + Lv[4]*t1 + Lv[8] *t2 + Lv[12]*t3);
                y.y = -(Lv[1]*t0 + Lv[5]*t1 + Lv[9] *t2 + Lv[13]*t3);
                y.z = -(Lv[2]*t0 + Lv[6]*t1 + Lv[10]*t2 + Lv[14]*t3);
                y.w = -(Lv[3]*t0 + Lv[7]*t1 + Lv[11]*t2 + Lv[15]*t3);
                x1 = y;
            }
            qf[u][cs] = (f16x8){(f16)(x0.x*sc2), (f16)(x0.y*sc2), (f16)(x0.z*sc2), (f16)(x0.w*sc2),
                                (f16)(x1.x*sc2), (f16)(x1.y*sc2), (f16)(x1.z*sc2), (f16)(x1.w*sc2)};
        }
    }

    f32x4 oacc[2][8];
    #pragma unroll
    for (int u = 0; u < 2; ++u)
        #pragma unroll
        for (int cb = 0; cb < 8; ++cb) oacc[u][cb] = (f32x4){0.f, 0.f, 0.f, 0.f};
    float mrun[2] = {-1e30f, -1e30f}, lrun[2] = {0.f, 0.f};

    for (int it = kh * 8; it < kh * 8 + 8; ++it) {    // 64 keys per iteration, half the keys
        const f16* kp = kbh + (size_t)it * 16 * 512;
        f16x8 kf[4][4];
        #pragma unroll
        for (int g = 0; g < 4; ++g)
            #pragma unroll
            for (int cs = 0; cs < 4; ++cs)
                kf[g][cs] = *(const f16x8*)(kp + (g * 4 + cs) * 512 + lane * 8);

        f32x4 s[2][4];
        #pragma unroll
        for (int u = 0; u < 2; ++u)
            #pragma unroll
            for (int g = 0; g < 4; ++g) s[u][g] = (f32x4){0.f, 0.f, 0.f, 0.f};
        #pragma unroll
        for (int g = 0; g < 4; ++g)
            #pragma unroll
            for (int cs = 0; cs < 4; ++cs) {
                s[0][g] = __builtin_amdgcn_mfma_f32_16x16x32_f16(kf[g][cs], qf[0][cs], s[0][g], 0, 0, 0);
                s[1][g] = __builtin_amdgcn_mfma_f32_16x16x32_f16(kf[g][cs], qf[1][cs], s[1][g], 0, 0, 0);
            }

        const f16* vp = vbh + (size_t)it * 2 * 8 * 512;
        f16x8 vf[2][8];
        #pragma unroll
        for (int k2 = 0; k2 < 2; ++k2)
            #pragma unroll
            for (int cb = 0; cb < 8; ++cb)
                vf[k2][cb] = *(const f16x8*)(vp + (k2 * 8 + cb) * 512 + lane * 8);

        // exp2-domain online softmax (scores already scaled by log2e)
        f16x8 pf[2][2];
        #pragma unroll
        for (int u = 0; u < 2; ++u) {
            float mx = -1e30f;
            #pragma unroll
            for (int g = 0; g < 4; ++g)
                mx = fmaxf(mx, fmaxf(fmaxf(s[u][g].x, s[u][g].y), fmaxf(s[u][g].z, s[u][g].w)));
            mx = fmaxf(mx, __shfl_xor(mx, 16, 64));
            mx = fmaxf(mx, __shfl_xor(mx, 32, 64));
            float mnew = fmaxf(mrun[u], mx);
            // defer-rescale (bit-exact): when no lane sees a new max, alpha==1 exactly
            if (!__all(mx <= mrun[u])) {
                float alpha = exp2f(mrun[u] - mnew);
                lrun[u] *= alpha;
                #pragma unroll
                for (int cb = 0; cb < 8; ++cb) oacc[u][cb] *= alpha;
                mrun[u] = mnew;
            }
            float p[16], rs = 0.f;
            #pragma unroll
            for (int g = 0; g < 4; ++g) {
                p[g*4+0] = exp2f(s[u][g].x - mnew);
                p[g*4+1] = exp2f(s[u][g].y - mnew);
                p[g*4+2] = exp2f(s[u][g].z - mnew);
                p[g*4+3] = exp2f(s[u][g].w - mnew);
                rs += (p[g*4+0] + p[g*4+1]) + (p[g*4+2] + p[g*4+3]);
            }
            rs += __shfl_xor(rs, 16, 64);
            rs += __shfl_xor(rs, 32, 64);
            lrun[u] += rs;
            pf[u][0] = (f16x8){(f16)p[0],(f16)p[1],(f16)p[2],(f16)p[3],(f16)p[4],(f16)p[5],(f16)p[6],(f16)p[7]};
            pf[u][1] = (f16x8){(f16)p[8],(f16)p[9],(f16)p[10],(f16)p[11],(f16)p[12],(f16)p[13],(f16)p[14],(f16)p[15]};
        }
        #pragma unroll
        for (int k2 = 0; k2 < 2; ++k2)
            #pragma unroll
            for (int cb = 0; cb < 8; ++cb) {
                oacc[0][cb] = __builtin_amdgcn_mfma_f32_16x16x32_f16(vf[k2][cb], pf[0][k2], oacc[0][cb], 0, 0, 0);
                oacc[1][cb] = __builtin_amdgcn_mfma_f32_16x16x32_f16(vf[k2][cb], pf[1][k2], oacc[1][cb], 0, 0, 0);
            }
    }

    // ---- pair merge: key-half 1 writes state, key-half 0 merges + epilogue ----
    if (kh) {
        float* dst = &mrg[w >> 1][lane][0];
        #pragma unroll
        for (int u = 0; u < 2; ++u)
            #pragma unroll
            for (int cb = 0; cb < 8; ++cb)
                *(f32x4*)&dst[u * 32 + cb * 4] = oacc[u][cb];
        dst[64] = mrun[0]; dst[65] = lrun[0]; dst[66] = mrun[1]; dst[67] = lrun[1];
    }
    __syncthreads();
    if (kh) return;

    const float* src = &mrg[w >> 1][lane][0];
    #pragma unroll
    for (int u = 0; u < 2; ++u) {
        float mB = src[64 + u * 2], lB = src[65 + u * 2];
        float m  = fmaxf(mrun[u], mB);
        float eA = exp2f(mrun[u] - m), eB = exp2f(mB - m);
        float l  = lrun[u] * eA + lB * eB;
        float invl = 1.0f / l;
        int qrow = q0 + u * 16 + lq;
        const float* Lr = Lm + ((size_t)b * NSEQ + qrow) * 16;
        float* ob = out + ((size_t)bh * NSEQ + qrow) * CD;
        #pragma unroll
        for (int cb = 0; cb < 8; ++cb) {
            f32x4 oB = *(const f32x4*)&src[u * 32 + cb * 4];
            int c0 = cb * 16 + quad * 4;
            float o0 = (oacc[u][cb].x * eA + oB.x * eB) * invl;
            float o1 = (oacc[u][cb].y * eA + oB.y * eB) * invl;
            float o2 = (oacc[u][cb].z * eA + oB.z * eB) * invl;
            float o3 = (oacc[u][cb].w * eA + oB.w * eB) * invl;
            float4 r;
            if (c0 >= 8) {
                r.x = Lr[0] *o0 + Lr[1] *o1 + Lr[2] *o2 + Lr[3] *o3;
                r.y = Lr[4] *o0 + Lr[5] *o1 + Lr[6] *o2 + Lr[7] *o3;
                r.z = Lr[8] *o0 + Lr[9] *o1 + Lr[10]*o2 + Lr[11]*o3;
                r.w = Lr[12]*o0 + Lr[13]*o1 + Lr[14]*o2 + Lr[15]*o3;
            } else {
                r.x = o0; r.y = o1; r.z = o2; r.w = o3;
            }
            *(float4*)(ob + c0) = r;
        }
    }
}

extern "C" void kernel_launch(void* const* d_in, const int* in_sizes, int n_in,
                              void* d_out, int out_size, void* d_ws, size_t ws_size,
                              hipStream_t stream) {
    const float* q = (const float*)d_in[0];
    const float* k = (const float*)d_in[1];
    const float* v = (const float*)d_in[2];
    const float* L = (const float*)d_in[3];
    float* o = (float*)d_out;
    f16* khs = (f16*)d_ws;                       // 16.78 MB
    f16* vhs = khs + (size_t)64 * 131072;        // 16.78 MB
    dim3 grid1(64, 16);
    ipa_pre<<<grid1, 256, 0, stream>>>(k, v, L, khs, vhs);
    ipa_attn<<<1024, 256, 0, stream>>>(q, khs, vhs, L, o);
}

// Round 2
// 195.669 us; speedup vs baseline: 2.5809x; 2.5809x over previous
//
#include <hip/hip_runtime.h>
#include <math.h>

typedef _Float16 f16;
typedef _Float16 f16x4 __attribute__((ext_vector_type(4)));
typedef _Float16 f16x8 __attribute__((ext_vector_type(8)));
typedef float    f32x4 __attribute__((ext_vector_type(4)));

#define NSEQ 1024
#define CD   128
#define LT   136   // pre-kernel LDS f16 row stride (272 B = 17*16 B, keeps b128 alignment)

// khs: [bh][g16 0..63][cs 0..3][lane 0..63][j 0..7]   (131072 f16 per bh)
//   value = Ktr[key = (g16>>1)*32 + 8*(lq>>2) + 4*(g16&1) + (lq&3)][c = cs*32+quad*8+j]
// vhs: [bh][k32 0..31][cb 0..7][lane 0..63][j 0..7]
//   value = Vtr[key = k32*32 + quad*8 + j][c = cb*16 + lq]
// Both are exact MFMA fragment order: a wave's frag load = base + lane*16B (coalesced 1KB).

__global__ __launch_bounds__(256)
void ipa_pre(const float* __restrict__ kg, const float* __restrict__ vg,
             const float* __restrict__ Lm, f16* __restrict__ khs, f16* __restrict__ vhs)
{
    __shared__ float LL[64 * 16];
    __shared__ __align__(16) f16 Kt[64 * LT];
    __shared__ __align__(16) f16 Vt[64 * LT];
    const int bx = blockIdx.x, nt = blockIdx.y, tid = threadIdx.x;
    const int bh = ((bx & 7) << 3) | (bx >> 3);   // XCD x <-> bh 8x..8x+7 (matches attn)
    const int b  = bh >> 3;
    const float* Lb = Lm + ((size_t)b * NSEQ + nt * 64) * 16;
    for (int t = tid; t < 64 * 16; t += 256) LL[t] = Lb[t];
    __syncthreads();

    const size_t base = ((size_t)bh * NSEQ + nt * 64) * CD;
    #pragma unroll
    for (int it = 0; it < 8; ++it) {
        int g = it * 256 + tid;
        int row = g >> 5, cg = g & 31;
        size_t idx = base + row * CD + cg * 4;
        const float* Lr = &LL[row * 16];
        float4 xk = *(const float4*)(kg + idx);
        float4 xv = *(const float4*)(vg + idx);
        float4 yk = xk, yv = xv;
        if (cg >= 2) {
            float t0 = xk.x, t1 = -xk.y, t2 = -xk.z, t3 = -xk.w;   // K: M = L^T eta
            yk.x = Lr[0]*t0 + Lr[4]*t1 + Lr[8] *t2 + Lr[12]*t3;
            yk.y = Lr[1]*t0 + Lr[5]*t1 + Lr[9] *t2 + Lr[13]*t3;
            yk.z = Lr[2]*t0 + Lr[6]*t1 + Lr[10]*t2 + Lr[14]*t3;
            yk.w = Lr[3]*t0 + Lr[7]*t1 + Lr[11]*t2 + Lr[15]*t3;
            t0 = xv.x; t1 = -xv.y; t2 = -xv.z; t3 = -xv.w;         // V: M = eta L^T eta
            yv.x =  (Lr[0]*t0 + Lr[4]*t1 + Lr[8] *t2 + Lr[12]*t3);
            yv.y = -(Lr[1]*t0 + Lr[5]*t1 + Lr[9] *t2 + Lr[13]*t3);
            yv.z = -(Lr[2]*t0 + Lr[6]*t1 + Lr[10]*t2 + Lr[14]*t3);
            yv.w = -(Lr[3]*t0 + Lr[7]*t1 + Lr[11]*t2 + Lr[15]*t3);
        }
        f16x4 hk = {(f16)yk.x, (f16)yk.y, (f16)yk.z, (f16)yk.w};
        f16x4 hv = {(f16)yv.x, (f16)yv.y, (f16)yv.z, (f16)yv.w};
        *(f16x4*)&Kt[row * LT + cg * 4] = hk;
        *(f16x4*)&Vt[row * LT + cg * 4] = hv;
    }
    __syncthreads();

    // staged K out (b128 LDS read -> fully coalesced global store)
    f16* kout = khs + (size_t)bh * 131072 + (size_t)nt * 4 * 4 * 512;
    #pragma unroll
    for (int it = 0; it < 4; ++it) {
        int slot = it * 256 + tid;                 // (g16l, cs, L)
        int g16l = slot >> 8, cs = (slot >> 6) & 3, L = slot & 63;
        int lq = L & 15, quad = L >> 4;
        int keyl = ((g16l >> 1) << 5) + ((lq >> 2) << 3) + ((g16l & 1) << 2) + (lq & 3);
        f16x8 kv = *(const f16x8*)&Kt[keyl * LT + cs * 32 + quad * 8];
        *(f16x8*)(kout + (g16l * 4 + cs) * 512 + L * 8) = kv;
    }
    // staged V^T out (scalar LDS column reads -> coalesced global store)
    f16* vout = vhs + (size_t)bh * 131072 + (size_t)nt * 2 * 8 * 512;
    #pragma unroll
    for (int it = 0; it < 4; ++it) {
        int slot = it * 256 + tid;                 // (k32l, cb, L)
        int k32l = slot >> 9, cb = (slot >> 6) & 7, L = slot & 63;
        int lq = L & 15, quad = L >> 4;
        int c = cb * 16 + lq;
        f16x8 o;
        #pragma unroll
        for (int j = 0; j < 8; ++j)
            o[j] = Vt[(k32l * 32 + quad * 8 + j) * LT + c];
        *(f16x8*)(vout + (k32l * 8 + cb) * 512 + L * 8) = o;
    }
}

// ---------------- attention: key-split flash, 4 waves/block ----------------
// Wave w: q-tile (w>>1), key-half (w&1).  Pairs merge (m,l,oacc) via LDS at the end.
// No barriers in the hot loop.  4096 waves total -> 4 waves/SIMD if VGPR<=128.
// NOTE: launch_bounds min-waves arg deliberately NOT set to 4 — forcing it made the
// allocator cap at 64 VGPR and spill ~1.6 GB to scratch (round 1). Cap 256, let the
// allocator land ~128 naturally (round 0 did exactly that with this loop body).
__global__ __launch_bounds__(256, 2)
void ipa_attn(const float* __restrict__ qg, const f16* __restrict__ khs,
              const f16* __restrict__ vhs, const float* __restrict__ Lm,
              float* __restrict__ out)
{
    __shared__ __align__(16) float mrg[2][64][68];   // [pair][lane][oacc 0..63, m0,l0,m1,l1]
    const int n = blockIdx.x;
    const int bh = ((n & 7) << 3) | ((n >> 3) & 7);   // XCD x (n%8) handles bh 8x..8x+7
    const int b  = bh >> 3;
    const int tid = threadIdx.x;
    const int w = tid >> 6, lane = tid & 63, lq = lane & 15, quad = lane >> 4;
    const int qw = (n >> 6) * 2 + (w >> 1);           // 0..31
    const int kh = w & 1;                             // key half
    const int q0 = qw * 32;
    const f16* kbh = khs + (size_t)bh * 131072;
    const f16* vbh = vhs + (size_t)bh * 131072;
    const float sc2 = 0.12751744154226873f;           // (1/sqrt(128)) * log2(e)

    // ---- Q: load fp32, transform (M = eta L^T eta) per-lane, scale, make frags ----
    f16x8 qf[2][4];
    #pragma unroll
    for (int u = 0; u < 2; ++u) {
        int qrow = q0 + u * 16 + lq;
        const float* Lr = Lm + ((size_t)b * NSEQ + qrow) * 16;
        const float* qp = qg + ((size_t)bh * NSEQ + qrow) * CD;
        float Lv[16];
        #pragma unroll
        for (int i = 0; i < 4; ++i) *(float4*)&Lv[i*4] = *(const float4*)(Lr + i*4);
        #pragma unroll
        for (int cs = 0; cs < 4; ++cs) {
            int c0 = cs * 32 + quad * 8;
            float4 x0 = *(const float4*)(qp + c0);
            float4 x1 = *(const float4*)(qp + c0 + 4);
            if (c0 >= 8) {
                float t0 = x0.x, t1 = -x0.y, t2 = -x0.z, t3 = -x0.w;
                float4 y;
                y.x =  (Lv[0]*t0 + Lv[4]*t1 + Lv[8] *t2 + Lv[12]*t3);
                y.y = -(Lv[1]*t0 + Lv[5]*t1 + Lv[9] *t2 + Lv[13]*t3);
                y.z = -(Lv[2]*t0 + Lv[6]*t1 + Lv[10]*t2 + Lv[14]*t3);
                y.w = -(Lv[3]*t0 + Lv[7]*t1 + Lv[11]*t2 + Lv[15]*t3);
                x0 = y;
                t0 = x1.x; t1 = -x1.y; t2 = -x1.z; t3 = -x1.w;
                y.x =  (Lv[0]*t0 + Lv[4]*t1 + Lv[8] *t2 + Lv[12]*t3);
                y.y = -(Lv[1]*t0 + Lv[5]*t1 + Lv[9] *t2 + Lv[13]*t3);
                y.z = -(Lv[2]*t0 + Lv[6]*t1 + Lv[10]*t2 + Lv[14]*t3);
                y.w = -(Lv[3]*t0 + Lv[7]*t1 + Lv[11]*t2 + Lv[15]*t3);
                x1 = y;
            }
            qf[u][cs] = (f16x8){(f16)(x0.x*sc2), (f16)(x0.y*sc2), (f16)(x0.z*sc2), (f16)(x0.w*sc2),
                                (f16)(x1.x*sc2), (f16)(x1.y*sc2), (f16)(x1.z*sc2), (f16)(x1.w*sc2)};
        }
    }

    f32x4 oacc[2][8];
    #pragma unroll
    for (int u = 0; u < 2; ++u)
        #pragma unroll
        for (int cb = 0; cb < 8; ++cb) oacc[u][cb] = (f32x4){0.f, 0.f, 0.f, 0.f};
    float mrun[2] = {-1e30f, -1e30f}, lrun[2] = {0.f, 0.f};

    for (int it = kh * 8; it < kh * 8 + 8; ++it) {    // 64 keys per iteration, half the keys
        const f16* kp = kbh + (size_t)it * 16 * 512;
        f16x8 kf[4][4];
        #pragma unroll
        for (int g = 0; g < 4; ++g)
            #pragma unroll
            for (int cs = 0; cs < 4; ++cs)
                kf[g][cs] = *(const f16x8*)(kp + (g * 4 + cs) * 512 + lane * 8);

        f32x4 s[2][4];
        #pragma unroll
        for (int u = 0; u < 2; ++u)
            #pragma unroll
            for (int g = 0; g < 4; ++g) s[u][g] = (f32x4){0.f, 0.f, 0.f, 0.f};
        #pragma unroll
        for (int g = 0; g < 4; ++g)
            #pragma unroll
            for (int cs = 0; cs < 4; ++cs) {
                s[0][g] = __builtin_amdgcn_mfma_f32_16x16x32_f16(kf[g][cs], qf[0][cs], s[0][g], 0, 0, 0);
                s[1][g] = __builtin_amdgcn_mfma_f32_16x16x32_f16(kf[g][cs], qf[1][cs], s[1][g], 0, 0, 0);
            }

        const f16* vp = vbh + (size_t)it * 2 * 8 * 512;
        f16x8 vf[2][8];
        #pragma unroll
        for (int k2 = 0; k2 < 2; ++k2)
            #pragma unroll
            for (int cb = 0; cb < 8; ++cb)
                vf[k2][cb] = *(const f16x8*)(vp + (k2 * 8 + cb) * 512 + lane * 8);

        // exp2-domain online softmax (scores already scaled by log2e)
        f16x8 pf[2][2];
        #pragma unroll
        for (int u = 0; u < 2; ++u) {
            float mx = -1e30f;
            #pragma unroll
            for (int g = 0; g < 4; ++g)
                mx = fmaxf(mx, fmaxf(fmaxf(s[u][g].x, s[u][g].y), fmaxf(s[u][g].z, s[u][g].w)));
            mx = fmaxf(mx, __shfl_xor(mx, 16, 64));
            mx = fmaxf(mx, __shfl_xor(mx, 32, 64));
            float mnew = fmaxf(mrun[u], mx);
            // defer-rescale (bit-exact): when no lane sees a new max, alpha==1 exactly
            if (!__all(mx <= mrun[u])) {
                float alpha = exp2f(mrun[u] - mnew);
                lrun[u] *= alpha;
                #pragma unroll
                for (int cb = 0; cb < 8; ++cb) oacc[u][cb] *= alpha;
                mrun[u] = mnew;
            }
            float p[16], rs = 0.f;
            #pragma unroll
            for (int g = 0; g < 4; ++g) {
                p[g*4+0] = exp2f(s[u][g].x - mnew);
                p[g*4+1] = exp2f(s[u][g].y - mnew);
                p[g*4+2] = exp2f(s[u][g].z - mnew);
                p[g*4+3] = exp2f(s[u][g].w - mnew);
                rs += (p[g*4+0] + p[g*4+1]) + (p[g*4+2] + p[g*4+3]);
            }
            rs += __shfl_xor(rs, 16, 64);
            rs += __shfl_xor(rs, 32, 64);
            lrun[u] += rs;
            pf[u][0] = (f16x8){(f16)p[0],(f16)p[1],(f16)p[2],(f16)p[3],(f16)p[4],(f16)p[5],(f16)p[6],(f16)p[7]};
            pf[u][1] = (f16x8){(f16)p[8],(f16)p[9],(f16)p[10],(f16)p[11],(f16)p[12],(f16)p[13],(f16)p[14],(f16)p[15]};
        }
        #pragma unroll
        for (int k2 = 0; k2 < 2; ++k2)
            #pragma unroll
            for (int cb = 0; cb < 8; ++cb) {
                oacc[0][cb] = __builtin_amdgcn_mfma_f32_16x16x32_f16(vf[k2][cb], pf[0][k2], oacc[0][cb], 0, 0, 0);
                oacc[1][cb] = __builtin_amdgcn_mfma_f32_16x16x32_f16(vf[k2][cb], pf[1][k2], oacc[1][cb], 0, 0, 0);
            }
    }

    // ---- pair merge: key-half 1 writes state, key-half 0 merges + epilogue ----
    if (kh) {
        float* dst = &mrg[w >> 1][lane][0];
        #pragma unroll
        for (int u = 0; u < 2; ++u)
            #pragma unroll
            for (int cb = 0; cb < 8; ++cb)
                *(f32x4*)&dst[u * 32 + cb * 4] = oacc[u][cb];
        dst[64] = mrun[0]; dst[65] = lrun[0]; dst[66] = mrun[1]; dst[67] = lrun[1];
    }
    __syncthreads();
    if (kh) return;

    const float* src = &mrg[w >> 1][lane][0];
    #pragma unroll
    for (int u = 0; u < 2; ++u) {
        float mB = src[64 + u * 2], lB = src[65 + u * 2];
        float m  = fmaxf(mrun[u], mB);
        float eA = exp2f(mrun[u] - m), eB = exp2f(mB - m);
        float l  = lrun[u] * eA + lB * eB;
        float invl = 1.0f / l;
        int qrow = q0 + u * 16 + lq;
        const float* Lr = Lm + ((size_t)b * NSEQ + qrow) * 16;
        float* ob = out + ((size_t)bh * NSEQ + qrow) * CD;
        #pragma unroll
        for (int cb = 0; cb < 8; ++cb) {
            f32x4 oB = *(const f32x4*)&src[u * 32 + cb * 4];
            int c0 = cb * 16 + quad * 4;
            float o0 = (oacc[u][cb].x * eA + oB.x * eB) * invl;
            float o1 = (oacc[u][cb].y * eA + oB.y * eB) * invl;
            float o2 = (oacc[u][cb].z * eA + oB.z * eB) * invl;
            float o3 = (oacc[u][cb].w * eA + oB.w * eB) * invl;
            float4 r;
            if (c0 >= 8) {
                r.x = Lr[0] *o0 + Lr[1] *o1 + Lr[2] *o2 + Lr[3] *o3;
                r.y = Lr[4] *o0 + Lr[5] *o1 + Lr[6] *o2 + Lr[7] *o3;
                r.z = Lr[8] *o0 + Lr[9] *o1 + Lr[10]*o2 + Lr[11]*o3;
                r.w = Lr[12]*o0 + Lr[13]*o1 + Lr[14]*o2 + Lr[15]*o3;
            } else {
                r.x = o0; r.y = o1; r.z = o2; r.w = o3;
            }
            *(float4*)(ob + c0) = r;
        }
    }
}

extern "C" void kernel_launch(void* const* d_in, const int* in_sizes, int n_in,
                              void* d_out, int out_size, void* d_ws, size_t ws_size,
                              hipStream_t stream) {
    const float* q = (const float*)d_in[0];
    const float* k = (const float*)d_in[1];
    const float* v = (const float*)d_in[2];
    const float* L = (const float*)d_in[3];
    float* o = (float*)d_out;
    f16* khs = (f16*)d_ws;                       // 16.78 MB
    f16* vhs = khs + (size_t)64 * 131072;        // 16.78 MB
    dim3 grid1(64, 16);
    ipa_pre<<<grid1, 256, 0, stream>>>(k, v, L, khs, vhs);
    ipa_attn<<<1024, 256, 0, stream>>>(q, khs, vhs, L, o);
}

// Round 3
// 189.362 us; speedup vs baseline: 2.6669x; 1.0333x over previous
//
#include <hip/hip_runtime.h>
#include <math.h>

typedef _Float16 f16;
typedef _Float16 f16x4 __attribute__((ext_vector_type(4)));
typedef _Float16 f16x8 __attribute__((ext_vector_type(8)));
typedef float    f32x4 __attribute__((ext_vector_type(4)));

typedef const __attribute__((address_space(1))) void gv_t;   // global
typedef __attribute__((address_space(3))) void lv_t;         // LDS

#define NSEQ 1024
#define CD   128
#define LT   136   // pre-kernel LDS f16 row stride (272 B = 17*16 B, keeps b128 alignment)

// khs: [bh][g16 0..63][cs 0..3][lane 0..63][j 0..7]   (131072 f16 per bh)
//   value = Ktr[key = (g16>>1)*32 + 8*(lq>>2) + 4*(g16&1) + (lq&3)][c = cs*32+quad*8+j]
// vhs: [bh][k32 0..31][cb 0..7][lane 0..63][j 0..7]
//   value = Vtr[key = k32*32 + quad*8 + j][c = cb*16 + lq]
// Both are exact MFMA fragment order AND exact linear order for global_load_lds staging.

__global__ __launch_bounds__(256)
void ipa_pre(const float* __restrict__ kg, const float* __restrict__ vg,
             const float* __restrict__ Lm, f16* __restrict__ khs, f16* __restrict__ vhs)
{
    __shared__ float LL[64 * 16];
    __shared__ __align__(16) f16 Kt[64 * LT];
    __shared__ __align__(16) f16 Vt[64 * LT];
    const int bx = blockIdx.x, nt = blockIdx.y, tid = threadIdx.x;
    const int bh = ((bx & 7) << 3) | (bx >> 3);   // XCD x <-> bh 8x..8x+7 (matches attn)
    const int b  = bh >> 3;
    const float* Lb = Lm + ((size_t)b * NSEQ + nt * 64) * 16;
    for (int t = tid; t < 64 * 16; t += 256) LL[t] = Lb[t];
    __syncthreads();

    const size_t base = ((size_t)bh * NSEQ + nt * 64) * CD;
    #pragma unroll
    for (int it = 0; it < 8; ++it) {
        int g = it * 256 + tid;
        int row = g >> 5, cg = g & 31;
        size_t idx = base + row * CD + cg * 4;
        const float* Lr = &LL[row * 16];
        float4 xk = *(const float4*)(kg + idx);
        float4 xv = *(const float4*)(vg + idx);
        float4 yk = xk, yv = xv;
        if (cg >= 2) {
            float t0 = xk.x, t1 = -xk.y, t2 = -xk.z, t3 = -xk.w;   // K: M = L^T eta
            yk.x = Lr[0]*t0 + Lr[4]*t1 + Lr[8] *t2 + Lr[12]*t3;
            yk.y = Lr[1]*t0 + Lr[5]*t1 + Lr[9] *t2 + Lr[13]*t3;
            yk.z = Lr[2]*t0 + Lr[6]*t1 + Lr[10]*t2 + Lr[14]*t3;
            yk.w = Lr[3]*t0 + Lr[7]*t1 + Lr[11]*t2 + Lr[15]*t3;
            t0 = xv.x; t1 = -xv.y; t2 = -xv.z; t3 = -xv.w;         // V: M = eta L^T eta
            yv.x =  (Lr[0]*t0 + Lr[4]*t1 + Lr[8] *t2 + Lr[12]*t3);
            yv.y = -(Lr[1]*t0 + Lr[5]*t1 + Lr[9] *t2 + Lr[13]*t3);
            yv.z = -(Lr[2]*t0 + Lr[6]*t1 + Lr[10]*t2 + Lr[14]*t3);
            yv.w = -(Lr[3]*t0 + Lr[7]*t1 + Lr[11]*t2 + Lr[15]*t3);
        }
        f16x4 hk = {(f16)yk.x, (f16)yk.y, (f16)yk.z, (f16)yk.w};
        f16x4 hv = {(f16)yv.x, (f16)yv.y, (f16)yv.z, (f16)yv.w};
        *(f16x4*)&Kt[row * LT + cg * 4] = hk;
        *(f16x4*)&Vt[row * LT + cg * 4] = hv;
    }
    __syncthreads();

    // staged K out (b128 LDS read -> fully coalesced global store)
    f16* kout = khs + (size_t)bh * 131072 + (size_t)nt * 4 * 4 * 512;
    #pragma unroll
    for (int it = 0; it < 4; ++it) {
        int slot = it * 256 + tid;                 // (g16l, cs, L)
        int g16l = slot >> 8, cs = (slot >> 6) & 3, L = slot & 63;
        int lq = L & 15, quad = L >> 4;
        int keyl = ((g16l >> 1) << 5) + ((lq >> 2) << 3) + ((g16l & 1) << 2) + (lq & 3);
        f16x8 kv = *(const f16x8*)&Kt[keyl * LT + cs * 32 + quad * 8];
        *(f16x8*)(kout + (g16l * 4 + cs) * 512 + L * 8) = kv;
    }
    // staged V^T out (scalar LDS column reads -> coalesced global store)
    f16* vout = vhs + (size_t)bh * 131072 + (size_t)nt * 2 * 8 * 512;
    #pragma unroll
    for (int it = 0; it < 4; ++it) {
        int slot = it * 256 + tid;                 // (k32l, cb, L)
        int k32l = slot >> 9, cb = (slot >> 6) & 7, L = slot & 63;
        int lq = L & 15, quad = L >> 4;
        int c = cb * 16 + lq;
        f16x8 o;
        #pragma unroll
        for (int j = 0; j < 8; ++j)
            o[j] = Vt[(k32l * 32 + quad * 8 + j) * LT + c];
        *(f16x8*)(vout + (k32l * 8 + cb) * 512 + L * 8) = o;
    }
}

// ---------------- attention: LDS-shared K/V, 4 waves/block, 2-phase dbuf ----------------
// All 4 waves consume the SAME K/V tile (fragments are q-independent): global traffic /4.
// Theory: R0/R2 were bound at ~23 B/cy/CU on the global L1-miss path (identical time at
// identical per-CU load count despite 2x waves). LDS serves frags at 256 B/cy instead.
// Staging uses global_load_lds (layout is already linear fragment order), double-buffered,
// one barrier per K-tile (2-phase template; the barrier's implicit vmcnt/lgkm drain gives
// both "stage complete" and "reads done before overwrite").
__global__ __launch_bounds__(256, 2)
void ipa_attn(const float* __restrict__ qg, const f16* __restrict__ khs,
              const f16* __restrict__ vhs, const float* __restrict__ Lm,
              float* __restrict__ out)
{
    __shared__ __align__(16) f16 sK[2][8192];   // 16 KB per buffer
    __shared__ __align__(16) f16 sV[2][8192];   // 16 KB per buffer
    const int n = blockIdx.x;                   // 512 blocks = 64 bh x 8 qblk
    const int bh = ((n & 7) << 3) | ((n >> 3) & 7);   // XCD-local bh group (matches pre)
    const int b  = bh >> 3;
    const int tid = threadIdx.x;
    const int w = tid >> 6, lane = tid & 63, lq = lane & 15, quad = lane >> 4;
    const int qblk = n >> 6;                    // 0..7
    const int q0 = qblk * 128 + w * 32;         // wave owns 32 q-rows
    const f16* kbh = khs + (size_t)bh * 131072;
    const f16* vbh = vhs + (size_t)bh * 131072;
    const float sc2 = 0.12751744154226873f;     // (1/sqrt(128)) * log2(e)

    // issue one K/V tile (16 KB + 16 KB) into LDS buffer nb; 8 x 1KB gl_lds per wave
    auto stage = [&](int nb, int it) {
        const char* kp = (const char*)(kbh + (size_t)it * 8192);
        const char* vp = (const char*)(vbh + (size_t)it * 8192);
        char* kd = (char*)&sK[nb][0];
        char* vd = (char*)&sV[nb][0];
        #pragma unroll
        for (int j = 0; j < 4; ++j) {
            int off = (w * 4 + j) * 1024;       // wave-uniform LDS dest; per-lane global src
            __builtin_amdgcn_global_load_lds((gv_t*)(kp + off + lane * 16),
                                             (lv_t*)(kd + off), 16, 0, 0);
            __builtin_amdgcn_global_load_lds((gv_t*)(vp + off + lane * 16),
                                             (lv_t*)(vd + off), 16, 0, 0);
        }
    };

    // ---- Q: load fp32, transform (M = eta L^T eta) per-lane, scale, make frags ----
    f16x8 qf[2][4];
    #pragma unroll
    for (int u = 0; u < 2; ++u) {
        int qrow = q0 + u * 16 + lq;
        const float* Lr = Lm + ((size_t)b * NSEQ + qrow) * 16;
        const float* qp = qg + ((size_t)bh * NSEQ + qrow) * CD;
        float Lv[16];
        #pragma unroll
        for (int i = 0; i < 4; ++i) *(float4*)&Lv[i*4] = *(const float4*)(Lr + i*4);
        #pragma unroll
        for (int cs = 0; cs < 4; ++cs) {
            int c0 = cs * 32 + quad * 8;
            float4 x0 = *(const float4*)(qp + c0);
            float4 x1 = *(const float4*)(qp + c0 + 4);
            if (c0 >= 8) {
                float t0 = x0.x, t1 = -x0.y, t2 = -x0.z, t3 = -x0.w;
                float4 y;
                y.x =  (Lv[0]*t0 + Lv[4]*t1 + Lv[8] *t2 + Lv[12]*t3);
                y.y = -(Lv[1]*t0 + Lv[5]*t1 + Lv[9] *t2 + Lv[13]*t3);
                y.z = -(Lv[2]*t0 + Lv[6]*t1 + Lv[10]*t2 + Lv[14]*t3);
                y.w = -(Lv[3]*t0 + Lv[7]*t1 + Lv[11]*t2 + Lv[15]*t3);
                x0 = y;
                t0 = x1.x; t1 = -x1.y; t2 = -x1.z; t3 = -x1.w;
                y.x =  (Lv[0]*t0 + Lv[4]*t1 + Lv[8] *t2 + Lv[12]*t3);
                y.y = -(Lv[1]*t0 + Lv[5]*t1 + Lv[9] *t2 + Lv[13]*t3);
                y.z = -(Lv[2]*t0 + Lv[6]*t1 + Lv[10]*t2 + Lv[14]*t3);
                y.w = -(Lv[3]*t0 + Lv[7]*t1 + Lv[11]*t2 + Lv[15]*t3);
                x1 = y;
            }
            qf[u][cs] = (f16x8){(f16)(x0.x*sc2), (f16)(x0.y*sc2), (f16)(x0.z*sc2), (f16)(x0.w*sc2),
                                (f16)(x1.x*sc2), (f16)(x1.y*sc2), (f16)(x1.z*sc2), (f16)(x1.w*sc2)};
        }
    }

    f32x4 oacc[2][8];
    #pragma unroll
    for (int u = 0; u < 2; ++u)
        #pragma unroll
        for (int cb = 0; cb < 8; ++cb) oacc[u][cb] = (f32x4){0.f, 0.f, 0.f, 0.f};
    float mrun[2] = {-1e30f, -1e30f}, lrun[2] = {0.f, 0.f};

    stage(0, 0);

    for (int it = 0; it < 16; ++it) {                 // 64 keys per iteration
        const int cur = it & 1;
        __syncthreads();                              // stage(cur) complete; prev reads done
        if (it < 15) stage(cur ^ 1, it + 1);          // overlap next-tile loads with compute

        const f16* kb = &sK[cur][0];
        const f16* vb = &sV[cur][0];
        f16x8 kf[4][4];
        #pragma unroll
        for (int g = 0; g < 4; ++g)
            #pragma unroll
            for (int cs = 0; cs < 4; ++cs)
                kf[g][cs] = *(const f16x8*)&kb[(g * 4 + cs) * 512 + lane * 8];

        f32x4 s[2][4];
        #pragma unroll
        for (int u = 0; u < 2; ++u)
            #pragma unroll
            for (int g = 0; g < 4; ++g) s[u][g] = (f32x4){0.f, 0.f, 0.f, 0.f};
        #pragma unroll
        for (int g = 0; g < 4; ++g)
            #pragma unroll
            for (int cs = 0; cs < 4; ++cs) {
                s[0][g] = __builtin_amdgcn_mfma_f32_16x16x32_f16(kf[g][cs], qf[0][cs], s[0][g], 0, 0, 0);
                s[1][g] = __builtin_amdgcn_mfma_f32_16x16x32_f16(kf[g][cs], qf[1][cs], s[1][g], 0, 0, 0);
            }

        f16x8 vf[2][8];
        #pragma unroll
        for (int k2 = 0; k2 < 2; ++k2)
            #pragma unroll
            for (int cb = 0; cb < 8; ++cb)
                vf[k2][cb] = *(const f16x8*)&vb[(k2 * 8 + cb) * 512 + lane * 8];

        // exp2-domain online softmax (scores already scaled by log2e)
        f16x8 pf[2][2];
        #pragma unroll
        for (int u = 0; u < 2; ++u) {
            float mx = -1e30f;
            #pragma unroll
            for (int g = 0; g < 4; ++g)
                mx = fmaxf(mx, fmaxf(fmaxf(s[u][g].x, s[u][g].y), fmaxf(s[u][g].z, s[u][g].w)));
            mx = fmaxf(mx, __shfl_xor(mx, 16, 64));
            mx = fmaxf(mx, __shfl_xor(mx, 32, 64));
            float mnew = fmaxf(mrun[u], mx);
            // defer-rescale (bit-exact): when no lane sees a new max, alpha==1 exactly
            if (!__all(mx <= mrun[u])) {
                float alpha = exp2f(mrun[u] - mnew);
                lrun[u] *= alpha;
                #pragma unroll
                for (int cb = 0; cb < 8; ++cb) oacc[u][cb] *= alpha;
                mrun[u] = mnew;
            }
            float p[16], rs = 0.f;
            #pragma unroll
            for (int g = 0; g < 4; ++g) {
                p[g*4+0] = exp2f(s[u][g].x - mnew);
                p[g*4+1] = exp2f(s[u][g].y - mnew);
                p[g*4+2] = exp2f(s[u][g].z - mnew);
                p[g*4+3] = exp2f(s[u][g].w - mnew);
                rs += (p[g*4+0] + p[g*4+1]) + (p[g*4+2] + p[g*4+3]);
            }
            rs += __shfl_xor(rs, 16, 64);
            rs += __shfl_xor(rs, 32, 64);
            lrun[u] += rs;
            pf[u][0] = (f16x8){(f16)p[0],(f16)p[1],(f16)p[2],(f16)p[3],(f16)p[4],(f16)p[5],(f16)p[6],(f16)p[7]};
            pf[u][1] = (f16x8){(f16)p[8],(f16)p[9],(f16)p[10],(f16)p[11],(f16)p[12],(f16)p[13],(f16)p[14],(f16)p[15]};
        }
        #pragma unroll
        for (int k2 = 0; k2 < 2; ++k2)
            #pragma unroll
            for (int cb = 0; cb < 8; ++cb) {
                oacc[0][cb] = __builtin_amdgcn_mfma_f32_16x16x32_f16(vf[k2][cb], pf[0][k2], oacc[0][cb], 0, 0, 0);
                oacc[1][cb] = __builtin_amdgcn_mfma_f32_16x16x32_f16(vf[k2][cb], pf[1][k2], oacc[1][cb], 0, 0, 0);
            }
    }

    // ---- epilogue: normalize, final frame transform (M = L), store ----
    #pragma unroll
    for (int u = 0; u < 2; ++u) {
        int qrow = q0 + u * 16 + lq;
        float invl = 1.0f / lrun[u];
        const float* Lr = Lm + ((size_t)b * NSEQ + qrow) * 16;
        float* ob = out + ((size_t)bh * NSEQ + qrow) * CD;
        #pragma unroll
        for (int cb = 0; cb < 8; ++cb) {
            int c0 = cb * 16 + quad * 4;
            float o0 = oacc[u][cb].x*invl, o1 = oacc[u][cb].y*invl;
            float o2 = oacc[u][cb].z*invl, o3 = oacc[u][cb].w*invl;
            float4 r;
            if (c0 >= 8) {
                r.x = Lr[0] *o0 + Lr[1] *o1 + Lr[2] *o2 + Lr[3] *o3;
                r.y = Lr[4] *o0 + Lr[5] *o1 + Lr[6] *o2 + Lr[7] *o3;
                r.z = Lr[8] *o0 + Lr[9] *o1 + Lr[10]*o2 + Lr[11]*o3;
                r.w = Lr[12]*o0 + Lr[13]*o1 + Lr[14]*o2 + Lr[15]*o3;
            } else {
                r.x = o0; r.y = o1; r.z = o2; r.w = o3;
            }
            *(float4*)(ob + c0) = r;
        }
    }
}

extern "C" void kernel_launch(void* const* d_in, const int* in_sizes, int n_in,
                              void* d_out, int out_size, void* d_ws, size_t ws_size,
                              hipStream_t stream) {
    const float* q = (const float*)d_in[0];
    const float* k = (const float*)d_in[1];
    const float* v = (const float*)d_in[2];
    const float* L = (const float*)d_in[3];
    float* o = (float*)d_out;
    f16* khs = (f16*)d_ws;                       // 16.78 MB
    f16* vhs = khs + (size_t)64 * 131072;        // 16.78 MB
    dim3 grid1(64, 16);
    ipa_pre<<<grid1, 256, 0, stream>>>(k, v, L, khs, vhs);
    ipa_attn<<<512, 256, 0, stream>>>(q, khs, vhs, L, o);
}